// Round 4
// baseline (3126.610 us; speedup 1.0000x reference)
//
#include <hip/hip_runtime.h>

#define NUM_CODES 1024
#define EMBED_DIM 256
#define NPIX      32768
#define NELEM     8388608

// d_out layout (float offsets):
//   [0, 8388608)             z_q final  (scratch before gather: see below)
//   8388608, 8388609         losses
//   [8388610, +32768)        indices (float)
// scratch inside z_q region (all consumed before gather overwrites):
//   zh  f16 [32768][256]  -> float offs 0        .. 4194304
//   eh  f16 [1024][256]   -> float offs 4194304  .. 4325376   (scaled x1024)
//   esq f32 [1024]        -> float offs 4325376
//   zsq f32 [32768]       -> float offs 4326400
#define LOSS_OFF 8388608
#define IDX_OFF  8388610
#define EH_F     4194304
#define ESQ_F    4325376
#define ZSQ_F    4326400

#define MARGIN   3.0e-3f
#define CAP      16

typedef _Float16 half_t;
typedef _Float16 half8 __attribute__((ext_vector_type(8)));
typedef _Float16 half4 __attribute__((ext_vector_type(4)));
typedef float    f32x4 __attribute__((ext_vector_type(4)));
typedef unsigned int u32;

// ---------------- K1a: ||e_k||^2  (UNCHANGED from Round 2 — bit-exact) ---------
__global__ void esq_kernel(const float* __restrict__ E, float* __restrict__ esq) {
    int w = threadIdx.x >> 6;
    int lane = threadIdx.x & 63;
    int k = blockIdx.x * 4 + w;
    const float* row = E + (size_t)k * EMBED_DIM;
    float s = 0.f;
    #pragma unroll
    for (int j = 0; j < EMBED_DIM; j += 64) { float v = row[j + lane]; s += v * v; }
    #pragma unroll
    for (int off = 32; off; off >>= 1) s += __shfl_down(s, off, 64);
    if (lane == 0) esq[k] = s;
}

// ---------------- K1b: E -> f16 (x1024, avoids f16 denormals) ------------------
__global__ void ecvt_kernel(const float* __restrict__ E, half_t* __restrict__ eh) {
    int i = (blockIdx.x * 256 + threadIdx.x) * 4;
    float4 v = *(const float4*)&E[i];
    half4 h;
    h[0] = (half_t)(v.x * 1024.f); h[1] = (half_t)(v.y * 1024.f);
    h[2] = (half_t)(v.z * 1024.f); h[3] = (half_t)(v.w * 1024.f);
    *(half4*)&eh[i] = h;
}

// ---------------- K2: z transpose -> zh f16 [px][c];  zsq (Round-2 order) ------
__global__ void zprep_kernel(const float* __restrict__ z, half_t* __restrict__ zh,
                             float* __restrict__ zsq) {
    __shared__ float zf[64 * 257];
    __shared__ float part[4][64];
    const int t = threadIdx.x;
    const int px_base = blockIdx.x * 64;
    const int b  = px_base >> 10;
    const int hw = px_base & 1023;
    {   // load + transpose + zsq partials (c ascending within each g: Round-2 order)
        int px = t & 63, g = t >> 6;
        const float* zp = z + ((size_t)b << 18) + hw + px;
        float s = 0.f;
        #pragma unroll 8
        for (int r = 0; r < 64; ++r) {
            int c = g * 64 + r;
            float v = zp[(size_t)c * 1024];
            s += v * v;
            zf[px * 257 + c] = v;
        }
        part[g][px] = s;
    }
    __syncthreads();
    if (t < 64)
        zsq[px_base + t] = (part[0][t] + part[1][t]) + (part[2][t] + part[3][t]);
    {   // pack f16 rows [px][256]
        int px = t >> 2, q = t & 3;
        half_t* dst = zh + (size_t)(px_base + px) * 256;
        #pragma unroll
        for (int s8 = 0; s8 < 16; ++s8) {
            int c0 = q * 64 + s8 * 4;
            half4 h;
            h[0] = (half_t)zf[px * 257 + c0 + 0];
            h[1] = (half_t)zf[px * 257 + c0 + 1];
            h[2] = (half_t)zf[px * 257 + c0 + 2];
            h[3] = (half_t)zf[px * 257 + c0 + 3];
            *(half4*)&dst[c0] = h;
        }
    }
}

// ---------------- K3: MFMA distances + approx-min + exact rescue ---------------
// block = 64 px, loops 8 kb-chunks of 128 codes. 4 waves: (wk=code half, wp=px half)
// Zs: f16 [64][264] (528B rows);  Es: f16 [128][136] (272B rows); rescue overlay zf f32 [64][257]
__launch_bounds__(256, 2)
__global__ void vq_mfma(const float* __restrict__ z, const float* __restrict__ E,
                        const half_t* __restrict__ zh, const half_t* __restrict__ ehp,
                        const float* __restrict__ esq, const float* __restrict__ zsq,
                        float* __restrict__ out, float* __restrict__ lossacc)
{
    __shared__ char lds_raw[68608];
    __shared__ u32 runmin[64];
    __shared__ u32 cnt[64];
    __shared__ u32 listd[64][CAP];
    __shared__ u32 listk[64][CAP];
    __shared__ float esqs[128];
    __shared__ float zsqs[64];

    half_t* Zs = (half_t*)lds_raw;              // [64][264]
    half_t* Es = (half_t*)(lds_raw + 33792);    // [128][136]
    float*  zf = (float*)lds_raw;               // rescue overlay [64][257]

    const int t  = threadIdx.x;
    const int l  = t & 63;
    const int wid = t >> 6;
    const int wk = wid >> 1, wp = wid & 1;
    const int l15 = l & 15, lg = l >> 4;
    const int px_base = blockIdx.x * 64;
    const int b  = px_base >> 10;
    const int hw = px_base & 1023;

    // ---- stage Z tile (once): zh[px_base+r][0..256) -> Zs padded ----
    {
        int r = t >> 2, sg = t & 3;
        const uint4* src = (const uint4*)(zh + (size_t)(px_base + r) * 256 + sg * 64);
        half_t* dst = Zs + r * 264 + sg * 64;
        #pragma unroll
        for (int i = 0; i < 8; ++i) *(uint4*)(dst + i * 8) = src[i];
    }
    if (t < 64) { runmin[t] = 0x7f800000u; cnt[t] = 0u; zsqs[t] = zsq[px_base + t]; }
    __syncthreads();

    // ---- persistent B-frags: zh for all 8 csteps x 2 px-groups ----
    half8 zfr[8][2];
    #pragma unroll
    for (int cs = 0; cs < 8; ++cs)
        #pragma unroll
        for (int pg = 0; pg < 2; ++pg)
            zfr[cs][pg] = *(const half8*)(Zs + (wp * 32 + pg * 16 + l15) * 264 + cs * 32 + lg * 8);

    const int pxl0 = wp * 32 + l15;       // block-local px for pg=0
    const int pxl1 = pxl0 + 16;           // pg=1

    #pragma unroll 1
    for (int kb = 0; kb < 8; ++kb) {
        f32x4 acc[4][2];
        #pragma unroll
        for (int kt = 0; kt < 4; ++kt)
            #pragma unroll
            for (int pg = 0; pg < 2; ++pg) acc[kt][pg] = (f32x4){0.f, 0.f, 0.f, 0.f};

        if (t < 128) esqs[t] = esq[kb * 128 + t];

        #pragma unroll
        for (int h = 0; h < 2; ++h) {
            __syncthreads();
            {   // stage E half: eh[kb*128+r][h*128 .. +128) -> Es
                int r = t >> 1, sg = t & 1;
                const uint4* src = (const uint4*)(ehp + (size_t)(kb * 128 + r) * 256 + h * 128 + sg * 64);
                half_t* dst = Es + r * 136 + sg * 64;
                #pragma unroll
                for (int i = 0; i < 8; ++i) *(uint4*)(dst + i * 8) = src[i];
            }
            __syncthreads();
            #pragma unroll
            for (int cs = 0; cs < 4; ++cs) {
                half8 ehf[4];
                #pragma unroll
                for (int kt = 0; kt < 4; ++kt)
                    ehf[kt] = *(const half8*)(Es + (wk * 64 + kt * 16 + l15) * 136 + cs * 32 + lg * 8);
                #pragma unroll
                for (int kt = 0; kt < 4; ++kt) {
                    acc[kt][0] = __builtin_amdgcn_mfma_f32_16x16x32_f16(ehf[kt], zfr[h * 4 + cs][0], acc[kt][0], 0, 0, 0);
                    acc[kt][1] = __builtin_amdgcn_mfma_f32_16x16x32_f16(ehf[kt], zfr[h * 4 + cs][1], acc[kt][1], 0, 0, 0);
                }
            }
        }

        // ---- fold: d~ = tmp - 2*dot/1024 ; per-px running min via atomicMin ----
        float lmin0 = 3.4e38f, lmin1 = 3.4e38f;
        #pragma unroll
        for (int kt = 0; kt < 4; ++kt)
            #pragma unroll
            for (int r = 0; r < 4; ++r) {
                int kl = wk * 64 + kt * 16 + lg * 4 + r;
                float eq = esqs[kl];
                float d0 = fmaf(-0.001953125f, acc[kt][0][r], zsqs[pxl0] + eq);
                float d1 = fmaf(-0.001953125f, acc[kt][1][r], zsqs[pxl1] + eq);
                acc[kt][0][r] = d0; acc[kt][1][r] = d1;
                lmin0 = fminf(lmin0, d0); lmin1 = fminf(lmin1, d1);
            }
        atomicMin(&runmin[pxl0], __float_as_uint(lmin0));
        atomicMin(&runmin[pxl1], __float_as_uint(lmin1));
        __syncthreads();
        float thr0 = __uint_as_float(runmin[pxl0]) + MARGIN;
        float thr1 = __uint_as_float(runmin[pxl1]) + MARGIN;
        #pragma unroll
        for (int kt = 0; kt < 4; ++kt)
            #pragma unroll
            for (int r = 0; r < 4; ++r) {
                int kg = kb * 128 + wk * 64 + kt * 16 + lg * 4 + r;
                float d0 = acc[kt][0][r], d1 = acc[kt][1][r];
                if (d0 <= thr0) {
                    u32 p = atomicAdd(&cnt[pxl0], 1u);
                    if (p < CAP) { listd[pxl0][p] = __float_as_uint(d0); listk[pxl0][p] = (u32)kg; }
                }
                if (d1 <= thr1) {
                    u32 p = atomicAdd(&cnt[pxl1], 1u);
                    if (p < CAP) { listd[pxl1][p] = __float_as_uint(d1); listk[pxl1][p] = (u32)kg; }
                }
            }
        __syncthreads();
    }

    // ---- rescue: stage f32 z rows (overlay), exact recompute of candidates ----
    {
        int px = t & 63, cg = t >> 6;
        const float* zp = z + ((size_t)b << 18) + hw + px;
        #pragma unroll 8
        for (int r = 0; r < 64; ++r) {
            int c = cg * 64 + r;
            zf[px * 257 + c] = zp[(size_t)c * 1024];
        }
    }
    __syncthreads();
    if (t < 64) {
        const int px = t;
        const float zq = zsqs[px];
        const float* zr = zf + px * 257;
        float thr = __uint_as_float(runmin[px]) + MARGIN;
        float bd = 3.4e38f; int bk = 0x7fffffff;
        u32 n = cnt[px];
        if (n <= CAP) {
            for (u32 i = 0; i < n; ++i) {
                float da = __uint_as_float(listd[px][i]);
                if (da > thr) continue;
                int k = (int)listk[px][i];
                const float* er = E + (size_t)k * EMBED_DIM;
                float a = 0.f;
                #pragma unroll 8
                for (int c = 0; c < 256; ++c) a = fmaf(zr[c], er[c], a);
                float tmp = zq + esq[k];
                float d = fmaf(-2.f, a, tmp);
                if (d < bd || (d == bd && k < bk)) { bd = d; bk = k; }
            }
        } else {  // overflow fallback: exact full scan (provably correct, ~never taken)
            for (int k = 0; k < NUM_CODES; ++k) {
                const float* er = E + (size_t)k * EMBED_DIM;
                float a = 0.f;
                #pragma unroll 8
                for (int c = 0; c < 256; ++c) a = fmaf(zr[c], er[c], a);
                float tmp = zq + esq[k];
                float d = fmaf(-2.f, a, tmp);
                if (d < bd || (d == bd && k < bk)) { bd = d; bk = k; }
            }
        }
        out[IDX_OFF + px_base + px] = (float)bk;
        float s = bd;   // exact ||z - e_k*||^2
        #pragma unroll
        for (int off = 32; off; off >>= 1) s += __shfl_down(s, off, 64);
        if (px == 0) atomicAdd(lossacc, s);
    }
}

// ---------------- K4: gather z_q + losses ----------------
__global__ void gather_kernel(const float* __restrict__ E, float* __restrict__ out,
                              const float* __restrict__ lossacc) {
    const int t = threadIdx.x;
    const int px_base = blockIdx.x * 64;
    const int b  = px_base >> 10;
    const int hw = px_base & 1023;
    int px = t & 63, cr = t >> 6;
    int k = (int)out[IDX_OFF + px_base + px];
    float* ob = out + ((size_t)b << 18) + hw + px;
    const float* er = E + (size_t)k * EMBED_DIM;
    #pragma unroll 4
    for (int r = 0; r < 64; ++r) {
        int c = cr * 64 + r;
        ob[(size_t)c * 1024] = er[c];
    }
    if (blockIdx.x == 0 && t == 0) {
        float L = lossacc[0] / (float)NELEM;
        out[LOSS_OFF]     = L;
        out[LOSS_OFF + 1] = 0.25f * L;
    }
}

extern "C" void kernel_launch(void* const* d_in, const int* in_sizes, int n_in,
                              void* d_out, int out_size, void* d_ws, size_t ws_size,
                              hipStream_t stream) {
    const float* z = (const float*)d_in[0];           // [32,256,32,32]
    const float* E = (const float*)d_in[1];           // [1024,256]
    float* out = (float*)d_out;
    float* ws  = (float*)d_ws;

    half_t* zh  = (half_t*)out;                       // scratch in z_q region
    half_t* ehp = (half_t*)(out + EH_F);
    float* esqp = out + ESQ_F;
    float* zsqp = out + ZSQ_F;

    hipMemsetAsync(d_ws, 0, 64, stream);
    esq_kernel  <<<NUM_CODES / 4, 256, 0, stream>>>(E, esqp);
    ecvt_kernel <<<NUM_CODES * EMBED_DIM / 1024, 256, 0, stream>>>(E, ehp);
    zprep_kernel<<<NPIX / 64, 256, 0, stream>>>(z, zh, zsqp);
    vq_mfma     <<<NPIX / 64, 256, 0, stream>>>(z, E, zh, ehp, esqp, zsqp, out, ws);
    gather_kernel<<<NPIX / 64, 256, 0, stream>>>(E, out, ws);
}

// Round 5
// 175.889 us; speedup vs baseline: 17.7761x; 17.7761x over previous
//
#include <hip/hip_runtime.h>

#define NUM_CODES 1024
#define EMBED_DIM 256
#define NPIX      32768
#define NELEM     8388608

// d_out layout (float offsets):
//   [0, 8388608)             z_q final  (scratch before gather: see below)
//   8388608, 8388609         losses
//   [8388610, +32768)        indices (float)
// scratch inside z_q region (all consumed before gather overwrites):
//   zh  f16 [32768][256]  -> float offs 0        .. 4194304
//   eh  f16 [1024][256]   -> float offs 4194304  .. 4325376   (scaled x1024)
//   esq f32 [1024]        -> float offs 4325376
//   zsq f32 [32768]       -> float offs 4326400
#define LOSS_OFF 8388608
#define IDX_OFF  8388610
#define EH_F     4194304
#define ESQ_F    4325376
#define ZSQ_F    4326400

#define MARGIN   1.0e-3f
#define CAP      16

typedef _Float16 half_t;
typedef _Float16 half8 __attribute__((ext_vector_type(8)));
typedef _Float16 half4 __attribute__((ext_vector_type(4)));
typedef float    f32x4 __attribute__((ext_vector_type(4)));
typedef unsigned int u32;
typedef unsigned long long u64;

// ---------------- K1a: ||e_k||^2  (UNCHANGED — bit-exact vs Round 2) ----------
__global__ void esq_kernel(const float* __restrict__ E, float* __restrict__ esq) {
    int w = threadIdx.x >> 6;
    int lane = threadIdx.x & 63;
    int k = blockIdx.x * 4 + w;
    const float* row = E + (size_t)k * EMBED_DIM;
    float s = 0.f;
    #pragma unroll
    for (int j = 0; j < EMBED_DIM; j += 64) { float v = row[j + lane]; s += v * v; }
    #pragma unroll
    for (int off = 32; off; off >>= 1) s += __shfl_down(s, off, 64);
    if (lane == 0) esq[k] = s;
}

// ---------------- K1b: E -> f16 (x1024, avoids f16 denormals) ------------------
__global__ void ecvt_kernel(const float* __restrict__ E, half_t* __restrict__ eh) {
    int i = (blockIdx.x * 256 + threadIdx.x) * 4;
    float4 v = *(const float4*)&E[i];
    half4 h;
    h[0] = (half_t)(v.x * 1024.f); h[1] = (half_t)(v.y * 1024.f);
    h[2] = (half_t)(v.z * 1024.f); h[3] = (half_t)(v.w * 1024.f);
    *(half4*)&eh[i] = h;
}

// ---------------- K2: z transpose -> zh f16 [px][c];  zsq (Round-2 order) ------
__global__ void zprep_kernel(const float* __restrict__ z, half_t* __restrict__ zh,
                             float* __restrict__ zsq) {
    __shared__ float zf[64 * 257];
    __shared__ float part[4][64];
    const int t = threadIdx.x;
    const int px_base = blockIdx.x * 64;
    const int b  = px_base >> 10;
    const int hw = px_base & 1023;
    {   // load + transpose + zsq partials (c ascending within each g: Round-2 order)
        int px = t & 63, g = t >> 6;
        const float* zp = z + ((size_t)b << 18) + hw + px;
        float s = 0.f;
        #pragma unroll 8
        for (int r = 0; r < 64; ++r) {
            int c = g * 64 + r;
            float v = zp[(size_t)c * 1024];
            s += v * v;
            zf[px * 257 + c] = v;
        }
        part[g][px] = s;
    }
    __syncthreads();
    if (t < 64)
        zsq[px_base + t] = (part[0][t] + part[1][t]) + (part[2][t] + part[3][t]);
    {   // pack f16 rows [px][256]
        int px = t >> 2, q = t & 3;
        half_t* dst = zh + (size_t)(px_base + px) * 256;
        #pragma unroll
        for (int s8 = 0; s8 < 16; ++s8) {
            int c0 = q * 64 + s8 * 4;
            half4 h;
            h[0] = (half_t)zf[px * 257 + c0 + 0];
            h[1] = (half_t)zf[px * 257 + c0 + 1];
            h[2] = (half_t)zf[px * 257 + c0 + 2];
            h[3] = (half_t)zf[px * 257 + c0 + 3];
            *(half4*)&dst[c0] = h;
        }
    }
}

// ---------------- K3: MFMA distances + approx-min + PARALLEL exact rescue ------
// block = 64 px, loops 8 kb-chunks of 128 codes. 4 waves: (wk=code half, wp=px half)
// Zs: f16 [64][264];  Es: f16 [128][136]; rescue overlay zf f32 [64][257]
__launch_bounds__(256, 2)
__global__ void vq_mfma(const float* __restrict__ z, const float* __restrict__ E,
                        const half_t* __restrict__ zh, const half_t* __restrict__ ehp,
                        const float* __restrict__ esq, const float* __restrict__ zsq,
                        float* __restrict__ out, float* __restrict__ lossacc)
{
    __shared__ char lds_raw[68608];
    __shared__ u32 runmin[64];
    __shared__ u32 cnt[64];
    __shared__ u32 listd[64][CAP];
    __shared__ u32 listk[64][CAP];
    __shared__ float esqs[128];
    __shared__ float zsqs[64];
    __shared__ u64 best64[64];

    half_t* Zs = (half_t*)lds_raw;              // [64][264]
    half_t* Es = (half_t*)(lds_raw + 33792);    // [128][136]
    float*  zf = (float*)lds_raw;               // rescue overlay [64][257]

    const int t  = threadIdx.x;
    const int l  = t & 63;
    const int wid = t >> 6;
    const int wk = wid >> 1, wp = wid & 1;
    const int l15 = l & 15, lg = l >> 4;
    const int px_base = blockIdx.x * 64;
    const int b  = px_base >> 10;
    const int hw = px_base & 1023;

    // ---- stage Z tile (once): zh[px_base+r][0..256) -> Zs padded ----
    {
        int r = t >> 2, sg = t & 3;
        const uint4* src = (const uint4*)(zh + (size_t)(px_base + r) * 256 + sg * 64);
        half_t* dst = Zs + r * 264 + sg * 64;
        #pragma unroll
        for (int i = 0; i < 8; ++i) *(uint4*)(dst + i * 8) = src[i];
    }
    if (t < 64) { runmin[t] = 0x7f800000u; cnt[t] = 0u; zsqs[t] = zsq[px_base + t]; }
    __syncthreads();

    // ---- persistent B-frags: zh for all 8 csteps x 2 px-groups ----
    half8 zfr[8][2];
    #pragma unroll
    for (int cs = 0; cs < 8; ++cs)
        #pragma unroll
        for (int pg = 0; pg < 2; ++pg)
            zfr[cs][pg] = *(const half8*)(Zs + (wp * 32 + pg * 16 + l15) * 264 + cs * 32 + lg * 8);

    const int pxl0 = wp * 32 + l15;       // block-local px for pg=0
    const int pxl1 = pxl0 + 16;           // pg=1

    #pragma unroll 1
    for (int kb = 0; kb < 8; ++kb) {
        f32x4 acc[4][2];
        #pragma unroll
        for (int kt = 0; kt < 4; ++kt)
            #pragma unroll
            for (int pg = 0; pg < 2; ++pg) acc[kt][pg] = (f32x4){0.f, 0.f, 0.f, 0.f};

        if (t < 128) esqs[t] = esq[kb * 128 + t];

        #pragma unroll
        for (int h = 0; h < 2; ++h) {
            __syncthreads();
            {   // stage E half: eh[kb*128+r][h*128 .. +128) -> Es
                int r = t >> 1, sg = t & 1;
                const uint4* src = (const uint4*)(ehp + (size_t)(kb * 128 + r) * 256 + h * 128 + sg * 64);
                half_t* dst = Es + r * 136 + sg * 64;
                #pragma unroll
                for (int i = 0; i < 8; ++i) *(uint4*)(dst + i * 8) = src[i];
            }
            __syncthreads();
            #pragma unroll
            for (int cs = 0; cs < 4; ++cs) {
                half8 ehf[4];
                #pragma unroll
                for (int kt = 0; kt < 4; ++kt)
                    ehf[kt] = *(const half8*)(Es + (wk * 64 + kt * 16 + l15) * 136 + cs * 32 + lg * 8);
                #pragma unroll
                for (int kt = 0; kt < 4; ++kt) {
                    acc[kt][0] = __builtin_amdgcn_mfma_f32_16x16x32_f16(ehf[kt], zfr[h * 4 + cs][0], acc[kt][0], 0, 0, 0);
                    acc[kt][1] = __builtin_amdgcn_mfma_f32_16x16x32_f16(ehf[kt], zfr[h * 4 + cs][1], acc[kt][1], 0, 0, 0);
                }
            }
        }

        // ---- fold: d~ = tmp - 2*dot/1024 ; per-px running min via atomicMin ----
        float lmin0 = 3.4e38f, lmin1 = 3.4e38f;
        #pragma unroll
        for (int kt = 0; kt < 4; ++kt)
            #pragma unroll
            for (int r = 0; r < 4; ++r) {
                int kl = wk * 64 + kt * 16 + lg * 4 + r;
                float eq = esqs[kl];
                float d0 = fmaf(-0.001953125f, acc[kt][0][r], zsqs[pxl0] + eq);
                float d1 = fmaf(-0.001953125f, acc[kt][1][r], zsqs[pxl1] + eq);
                acc[kt][0][r] = d0; acc[kt][1][r] = d1;
                lmin0 = fminf(lmin0, d0); lmin1 = fminf(lmin1, d1);
            }
        atomicMin(&runmin[pxl0], __float_as_uint(lmin0));
        atomicMin(&runmin[pxl1], __float_as_uint(lmin1));
        __syncthreads();
        float thr0 = __uint_as_float(runmin[pxl0]) + MARGIN;
        float thr1 = __uint_as_float(runmin[pxl1]) + MARGIN;
        #pragma unroll
        for (int kt = 0; kt < 4; ++kt)
            #pragma unroll
            for (int r = 0; r < 4; ++r) {
                int kg = kb * 128 + wk * 64 + kt * 16 + lg * 4 + r;
                float d0 = acc[kt][0][r], d1 = acc[kt][1][r];
                if (d0 <= thr0) {
                    u32 p = atomicAdd(&cnt[pxl0], 1u);
                    if (p < CAP) { listd[pxl0][p] = __float_as_uint(d0); listk[pxl0][p] = (u32)kg; }
                }
                if (d1 <= thr1) {
                    u32 p = atomicAdd(&cnt[pxl1], 1u);
                    if (p < CAP) { listd[pxl1][p] = __float_as_uint(d1); listk[pxl1][p] = (u32)kg; }
                }
            }
        __syncthreads();
    }

    // ---- rescue: stage f32 z rows (overlay), exact recompute of candidates ----
    // Each candidate dot is the SAME sequential c=0..255 fma chain as Round 2
    // (bit-exact tie semantics); merge via packed (d_bits,k) u64 atomicMin
    // (lexicographic: d asc, then k asc — positive floats order as uints).
    {
        int px = t & 63, cg = t >> 6;
        const float* zp = z + ((size_t)b << 18) + hw + px;
        #pragma unroll 8
        for (int r = 0; r < 64; ++r) {
            int c = cg * 64 + r;
            zf[px * 257 + c] = zp[(size_t)c * 1024];
        }
    }
    if (t < 64) best64[t] = 0xFFFFFFFFFFFFFFFFull;
    __syncthreads();

    // A) candidate verification: 4 threads per pixel split the list
    {
        int px = t >> 2, j = t & 3;
        u32 n = cnt[px];
        if (n <= CAP) {
            float thr = __uint_as_float(runmin[px]) + MARGIN;
            const float zq = zsqs[px];
            const float* zr = zf + px * 257;
            for (u32 i = j; i < n; i += 4) {
                float da = __uint_as_float(listd[px][i]);
                if (da > thr) continue;
                int k = (int)listk[px][i];
                const float* er = E + (size_t)k * EMBED_DIM;
                float a = 0.f;
                #pragma unroll 8
                for (int c = 0; c < 256; ++c) a = fmaf(zr[c], er[c], a);
                float d = fmaf(-2.f, a, zq + esq[k]);
                u64 pk = ((u64)__float_as_uint(d) << 32) | (u32)k;
                atomicMin(&best64[px], pk);
            }
        }
    }
    __syncthreads();

    // B) overflow fallback (rare): all 256 threads cooperatively full-scan
    for (int px = 0; px < 64; ++px) {
        if (cnt[px] <= CAP) continue;          // uniform branch (LDS broadcast)
        const float zq = zsqs[px];
        const float* zr = zf + px * 257;
        for (int k = t; k < NUM_CODES; k += 256) {
            const float* er = E + (size_t)k * EMBED_DIM;
            float a = 0.f;
            #pragma unroll 8
            for (int c = 0; c < 256; ++c) a = fmaf(zr[c], er[c], a);
            float d = fmaf(-2.f, a, zq + esq[k]);
            u64 pk = ((u64)__float_as_uint(d) << 32) | (u32)k;
            atomicMin(&best64[px], pk);
        }
        __syncthreads();
    }
    __syncthreads();

    if (t < 64) {
        u64 pk = best64[t];
        int bk = (int)(u32)(pk & 0xFFFFFFFFull);
        float bd = __uint_as_float((u32)(pk >> 32));
        out[IDX_OFF + px_base + t] = (float)bk;
        float s = bd;   // exact ||z - e_k*||^2
        #pragma unroll
        for (int off = 32; off; off >>= 1) s += __shfl_down(s, off, 64);
        if (t == 0) atomicAdd(lossacc, s);
    }
}

// ---------------- K4: gather z_q + losses ----------------
__global__ void gather_kernel(const float* __restrict__ E, float* __restrict__ out,
                              const float* __restrict__ lossacc) {
    const int t = threadIdx.x;
    const int px_base = blockIdx.x * 64;
    const int b  = px_base >> 10;
    const int hw = px_base & 1023;
    int px = t & 63, cr = t >> 6;
    int k = (int)out[IDX_OFF + px_base + px];
    float* ob = out + ((size_t)b << 18) + hw + px;
    const float* er = E + (size_t)k * EMBED_DIM;
    #pragma unroll 4
    for (int r = 0; r < 64; ++r) {
        int c = cr * 64 + r;
        ob[(size_t)c * 1024] = er[c];
    }
    if (blockIdx.x == 0 && t == 0) {
        float L = lossacc[0] / (float)NELEM;
        out[LOSS_OFF]     = L;
        out[LOSS_OFF + 1] = 0.25f * L;
    }
}

extern "C" void kernel_launch(void* const* d_in, const int* in_sizes, int n_in,
                              void* d_out, int out_size, void* d_ws, size_t ws_size,
                              hipStream_t stream) {
    const float* z = (const float*)d_in[0];           // [32,256,32,32]
    const float* E = (const float*)d_in[1];           // [1024,256]
    float* out = (float*)d_out;
    float* ws  = (float*)d_ws;

    half_t* zh  = (half_t*)out;                       // scratch in z_q region
    half_t* ehp = (half_t*)(out + EH_F);
    float* esqp = out + ESQ_F;
    float* zsqp = out + ZSQ_F;

    hipMemsetAsync(d_ws, 0, 64, stream);
    esq_kernel  <<<NUM_CODES / 4, 256, 0, stream>>>(E, esqp);
    ecvt_kernel <<<NUM_CODES * EMBED_DIM / 1024, 256, 0, stream>>>(E, ehp);
    zprep_kernel<<<NPIX / 64, 256, 0, stream>>>(z, zh, zsqp);
    vq_mfma     <<<NPIX / 64, 256, 0, stream>>>(z, E, zh, ehp, esqp, zsqp, out, ws);
    gather_kernel<<<NPIX / 64, 256, 0, stream>>>(E, out, ws);
}

// Round 6
// 164.325 us; speedup vs baseline: 19.0270x; 1.0704x over previous
//
#include <hip/hip_runtime.h>

#define NUM_CODES 1024
#define EMBED_DIM 256
#define NPIX      32768
#define NELEM     8388608

// d_out layout (float offsets):
//   [0, 8388608)             z_q final  (scratch before gather: see below)
//   8388608, 8388609         losses
//   [8388610, +32768)        indices (float)
// scratch inside z_q region (all consumed before gather overwrites):
//   zh  f16 [32768][256]  -> float offs 0        .. 4194304
//   eh  f16 [1024][256]   -> float offs 4194304  .. 4325376   (scaled x1024)
//   esq f32 [1024]        -> float offs 4325376
//   zsq f32 [32768]       -> float offs 4326400
#define LOSS_OFF 8388608
#define IDX_OFF  8388610
#define EH_F     4194304
#define ESQ_F    4325376
#define ZSQ_F    4326400

#define MARGIN   1.0e-3f
#define CAP      16

typedef _Float16 half_t;
typedef _Float16 half8 __attribute__((ext_vector_type(8)));
typedef _Float16 half4 __attribute__((ext_vector_type(4)));
typedef float    f32x4 __attribute__((ext_vector_type(4)));
typedef unsigned int u32;
typedef unsigned long long u64;

// async global->LDS, 16B per lane; dest = uniform base + lane*16
#define GLD16(gsrc, ldst) \
    __builtin_amdgcn_global_load_lds((const __attribute__((address_space(1))) unsigned int*)(gsrc), \
                                     (__attribute__((address_space(3))) unsigned int*)(ldst), 16, 0, 0)

// ---------------- K1a: ||e_k||^2  (UNCHANGED — bit-exact vs Round 2) ----------
__global__ void esq_kernel(const float* __restrict__ E, float* __restrict__ esq) {
    int w = threadIdx.x >> 6;
    int lane = threadIdx.x & 63;
    int k = blockIdx.x * 4 + w;
    const float* row = E + (size_t)k * EMBED_DIM;
    float s = 0.f;
    #pragma unroll
    for (int j = 0; j < EMBED_DIM; j += 64) { float v = row[j + lane]; s += v * v; }
    #pragma unroll
    for (int off = 32; off; off >>= 1) s += __shfl_down(s, off, 64);
    if (lane == 0) esq[k] = s;
}

// ---------------- K1b: E -> f16 (x1024, avoids f16 denormals) ------------------
__global__ void ecvt_kernel(const float* __restrict__ E, half_t* __restrict__ eh) {
    int i = (blockIdx.x * 256 + threadIdx.x) * 4;
    float4 v = *(const float4*)&E[i];
    half4 h;
    h[0] = (half_t)(v.x * 1024.f); h[1] = (half_t)(v.y * 1024.f);
    h[2] = (half_t)(v.z * 1024.f); h[3] = (half_t)(v.w * 1024.f);
    *(half4*)&eh[i] = h;
}

// ---------------- K2: z transpose -> zh f16 [px][c];  zsq  (UNCHANGED) ---------
__global__ void zprep_kernel(const float* __restrict__ z, half_t* __restrict__ zh,
                             float* __restrict__ zsq) {
    __shared__ float zf[64 * 257];
    __shared__ float part[4][64];
    const int t = threadIdx.x;
    const int px_base = blockIdx.x * 64;
    const int b  = px_base >> 10;
    const int hw = px_base & 1023;
    {
        int px = t & 63, g = t >> 6;
        const float* zp = z + ((size_t)b << 18) + hw + px;
        float s = 0.f;
        #pragma unroll 8
        for (int r = 0; r < 64; ++r) {
            int c = g * 64 + r;
            float v = zp[(size_t)c * 1024];
            s += v * v;
            zf[px * 257 + c] = v;
        }
        part[g][px] = s;
    }
    __syncthreads();
    if (t < 64)
        zsq[px_base + t] = (part[0][t] + part[1][t]) + (part[2][t] + part[3][t]);
    {
        int px = t >> 2, q = t & 3;
        half_t* dst = zh + (size_t)(px_base + px) * 256;
        #pragma unroll
        for (int s8 = 0; s8 < 16; ++s8) {
            int c0 = q * 64 + s8 * 4;
            half4 h;
            h[0] = (half_t)zf[px * 257 + c0 + 0];
            h[1] = (half_t)zf[px * 257 + c0 + 1];
            h[2] = (half_t)zf[px * 257 + c0 + 2];
            h[3] = (half_t)zf[px * 257 + c0 + 3];
            *(half4*)&dst[c0] = h;
        }
    }
}

// ---------------- K3: pipelined MFMA distances + approx-min + exact rescue -----
// 64 px/block, 4 waves (wk=code half, wp=px half). E staged via global_load_lds
// into double-buffered 16KB quarters (64 chans), counted vmcnt(4), raw barriers.
// LDS Es layout: linear [128 codes][64 ch] f16 (128B rows), content XOR-swizzled
// (byte ^= ((row&7)<<4)) via pre-swizzled per-lane SOURCE addrs; frag ds_read
// applies the same XOR -> 2-way banks (free). Z frags come straight from global.
__launch_bounds__(256, 2)
__global__ void vq_mfma(const float* __restrict__ z, const float* __restrict__ E,
                        const half_t* __restrict__ zh, const half_t* __restrict__ ehp,
                        const float* __restrict__ esq, const float* __restrict__ zsq,
                        float* __restrict__ out, float* __restrict__ lossacc)
{
    __shared__ char lds_raw[65792];   // [0,32768): Es dbuf 2x16KB; rescue overlay zf f32[64][257]
    __shared__ float esqs[1024];
    __shared__ u32 runmin[64];
    __shared__ u32 cnt[64];
    __shared__ u32 listd[64][CAP];
    __shared__ u32 listk[64][CAP];
    __shared__ float zsqs[64];
    __shared__ u64 best64[64];

    const int t  = threadIdx.x;
    const int l  = t & 63;
    const int wid = t >> 6;
    const int wk = wid >> 1, wp = wid & 1;
    const int l15 = l & 15, lg = l >> 4;
    const int px_base = blockIdx.x * 64;
    const int b  = px_base >> 10;
    const int hw = px_base & 1023;

    // ---- DMA source addressing: wave wid stages rows [wid*32, wid*32+32) of the
    // 128-code chunk; instr i covers 8 rows; lane: row += l>>3, chunk (l&7)*16B,
    // with inverse-XOR pre-swizzle so LDS holds swizzled content.
    const int rloc = l >> 3;
    const int cswz = ((l & 7) ^ rloc) << 4;
    const char* srcbase = (const char*)ehp + (size_t)(wid * 32 + rloc) * 512 + cswz;
    char* EsL = (char*)lds_raw;
    char* dst0 = EsL + (wid * 4) * 1024;

    // issue phase-0 DMA (kb=0, q=0) into buf0
    GLD16(srcbase,         dst0);
    GLD16(srcbase + 4096,  dst0 + 1024);
    GLD16(srcbase + 8192,  dst0 + 2048);
    GLD16(srcbase + 12288, dst0 + 3072);

    // prologue staging
    #pragma unroll
    for (int i = 0; i < 4; ++i) esqs[t + i * 256] = esq[t + i * 256];
    if (t < 64) { runmin[t] = 0x7f800000u; cnt[t] = 0u; zsqs[t] = zsq[px_base + t]; }

    // persistent Z B-frags straight from global zh (L2-resident)
    half8 zfr[8][2];
    #pragma unroll
    for (int cs = 0; cs < 8; ++cs)
        #pragma unroll
        for (int pg = 0; pg < 2; ++pg)
            zfr[cs][pg] = *(const half8*)(zh + (size_t)(px_base + wp * 32 + pg * 16 + l15) * 256 + cs * 32 + lg * 8);

    const int pxl0 = wp * 32 + l15;
    const int pxl1 = pxl0 + 16;

    // per-lane frag read offsets in a quarter buffer (XOR-swizzled)
    int ebase[4], cofs[2];
    #pragma unroll
    for (int kt = 0; kt < 4; ++kt) ebase[kt] = (wk * 64 + kt * 16 + l15) * 128;
    #pragma unroll
    for (int csl = 0; csl < 2; ++csl) cofs[csl] = (csl * 64 + lg * 16) ^ ((l15 & 7) << 4);

    __syncthreads();   // esqs/zsqs/runmin visible; drains vmcnt -> buf0 ready
    const float zq0 = zsqs[pxl0];
    const float zq1 = zsqs[pxl1];

    #pragma unroll 1
    for (int kb = 0; kb < 8; ++kb) {
        f32x4 acc[4][2];
        #pragma unroll
        for (int kt = 0; kt < 4; ++kt)
            #pragma unroll
            for (int pg = 0; pg < 2; ++pg) acc[kt][pg] = (f32x4){0.f, 0.f, 0.f, 0.f};

        #pragma unroll
        for (int q = 0; q < 4; ++q) {
            // [A] issue DMA for next quarter into the other buffer, then counted wait
            if (q < 3 || kb < 7) {
                const size_t soff = (q < 3) ? ((size_t)kb * 65536 + (size_t)(q + 1) * 128)
                                            : ((size_t)(kb + 1) * 65536);
                const char* src = srcbase + soff;
                char* dst = EsL + ((q + 1) & 1) * 16384 + (wid * 4) * 1024;
                GLD16(src,         dst);
                GLD16(src + 4096,  dst + 1024);
                GLD16(src + 8192,  dst + 2048);
                GLD16(src + 12288, dst + 3072);
                asm volatile("s_waitcnt vmcnt(4)" ::: "memory");   // quarter q landed; q+1 in flight
            } else {
                asm volatile("s_waitcnt vmcnt(0)" ::: "memory");
            }
            __builtin_amdgcn_s_barrier();          // all waves' quarter-q DMA done
            asm volatile("" ::: "memory");
            // [D] consume quarter q
            const char* Eq = EsL + (q & 1) * 16384;
            #pragma unroll
            for (int kt = 0; kt < 4; ++kt) {
                #pragma unroll
                for (int csl = 0; csl < 2; ++csl) {
                    half8 ef = *(const half8*)(Eq + ebase[kt] + cofs[csl]);
                    acc[kt][0] = __builtin_amdgcn_mfma_f32_16x16x32_f16(ef, zfr[q * 2 + csl][0], acc[kt][0], 0, 0, 0);
                    acc[kt][1] = __builtin_amdgcn_mfma_f32_16x16x32_f16(ef, zfr[q * 2 + csl][1], acc[kt][1], 0, 0, 0);
                }
            }
            asm volatile("" ::: "memory");
            __builtin_amdgcn_s_barrier();          // all waves done reading buf[q&1]
        }

        // ---- fold (numerics byte-identical to verified Round-2 semantics) ----
        float lmin0 = 3.4e38f, lmin1 = 3.4e38f;
        #pragma unroll
        for (int kt = 0; kt < 4; ++kt) {
            f32x4 eqv = *(const f32x4*)&esqs[kb * 128 + wk * 64 + kt * 16 + lg * 4];
            #pragma unroll
            for (int r = 0; r < 4; ++r) {
                float d0 = fmaf(-0.001953125f, acc[kt][0][r], zq0 + eqv[r]);
                float d1 = fmaf(-0.001953125f, acc[kt][1][r], zq1 + eqv[r]);
                acc[kt][0][r] = d0; acc[kt][1][r] = d1;
                lmin0 = fminf(lmin0, d0); lmin1 = fminf(lmin1, d1);
            }
        }
        atomicMin(&runmin[pxl0], __float_as_uint(lmin0));
        atomicMin(&runmin[pxl1], __float_as_uint(lmin1));
        asm volatile("s_waitcnt lgkmcnt(0)" ::: "memory");  // DS atomics retired
        __builtin_amdgcn_s_barrier();
        asm volatile("" ::: "memory");
        float thr0 = __uint_as_float(runmin[pxl0]) + MARGIN;
        float thr1 = __uint_as_float(runmin[pxl1]) + MARGIN;
        #pragma unroll
        for (int kt = 0; kt < 4; ++kt)
            #pragma unroll
            for (int r = 0; r < 4; ++r) {
                int kg = kb * 128 + wk * 64 + kt * 16 + lg * 4 + r;
                float d0 = acc[kt][0][r], d1 = acc[kt][1][r];
                if (d0 <= thr0) {
                    u32 p = atomicAdd(&cnt[pxl0], 1u);
                    if (p < CAP) { listd[pxl0][p] = __float_as_uint(d0); listk[pxl0][p] = (u32)kg; }
                }
                if (d1 <= thr1) {
                    u32 p = atomicAdd(&cnt[pxl1], 1u);
                    if (p < CAP) { listd[pxl1][p] = __float_as_uint(d1); listk[pxl1][p] = (u32)kg; }
                }
            }
    }
    __syncthreads();   // all appends visible; Es dead

    // ---- rescue: stage f32 z rows (overlay), exact recompute of candidates ----
    float* zf = (float*)lds_raw;   // [64][257]
    {
        int px = t & 63, cg = t >> 6;
        const float* zp = z + ((size_t)b << 18) + hw + px;
        #pragma unroll 8
        for (int r = 0; r < 64; ++r) {
            int c = cg * 64 + r;
            zf[px * 257 + c] = zp[(size_t)c * 1024];
        }
    }
    if (t < 64) best64[t] = 0xFFFFFFFFFFFFFFFFull;
    __syncthreads();

    // A) candidate verification: 4 threads per pixel split the list
    {
        int px = t >> 2, j = t & 3;
        u32 n = cnt[px];
        if (n <= CAP) {
            float thr = __uint_as_float(runmin[px]) + MARGIN;
            const float zq = zsqs[px];
            const float* zr = zf + px * 257;
            for (u32 i = j; i < n; i += 4) {
                float da = __uint_as_float(listd[px][i]);
                if (da > thr) continue;
                int k = (int)listk[px][i];
                const float* er = E + (size_t)k * EMBED_DIM;
                float a = 0.f;
                #pragma unroll 8
                for (int c = 0; c < 256; ++c) a = fmaf(zr[c], er[c], a);
                float d = fmaf(-2.f, a, zq + esq[k]);
                u64 pk = ((u64)__float_as_uint(d) << 32) | (u32)k;
                atomicMin(&best64[px], pk);
            }
        }
    }
    __syncthreads();

    // B) overflow fallback (rare): all 256 threads cooperatively full-scan
    for (int px = 0; px < 64; ++px) {
        if (cnt[px] <= CAP) continue;          // uniform branch
        const float zq = zsqs[px];
        const float* zr = zf + px * 257;
        for (int k = t; k < NUM_CODES; k += 256) {
            const float* er = E + (size_t)k * EMBED_DIM;
            float a = 0.f;
            #pragma unroll 8
            for (int c = 0; c < 256; ++c) a = fmaf(zr[c], er[c], a);
            float d = fmaf(-2.f, a, zq + esq[k]);
            u64 pk = ((u64)__float_as_uint(d) << 32) | (u32)k;
            atomicMin(&best64[px], pk);
        }
        __syncthreads();
    }
    __syncthreads();

    if (t < 64) {
        u64 pk = best64[t];
        int bk = (int)(u32)(pk & 0xFFFFFFFFull);
        float bd = __uint_as_float((u32)(pk >> 32));
        out[IDX_OFF + px_base + t] = (float)bk;
        float s = bd;   // exact ||z - e_k*||^2
        #pragma unroll
        for (int off = 32; off; off >>= 1) s += __shfl_down(s, off, 64);
        if (t == 0) atomicAdd(lossacc, s);
    }
}

// ---------------- K4: gather z_q + losses (UNCHANGED) ----------------
__global__ void gather_kernel(const float* __restrict__ E, float* __restrict__ out,
                              const float* __restrict__ lossacc) {
    const int t = threadIdx.x;
    const int px_base = blockIdx.x * 64;
    const int b  = px_base >> 10;
    const int hw = px_base & 1023;
    int px = t & 63, cr = t >> 6;
    int k = (int)out[IDX_OFF + px_base + px];
    float* ob = out + ((size_t)b << 18) + hw + px;
    const float* er = E + (size_t)k * EMBED_DIM;
    #pragma unroll 4
    for (int r = 0; r < 64; ++r) {
        int c = cr * 64 + r;
        ob[(size_t)c * 1024] = er[c];
    }
    if (blockIdx.x == 0 && t == 0) {
        float L = lossacc[0] / (float)NELEM;
        out[LOSS_OFF]     = L;
        out[LOSS_OFF + 1] = 0.25f * L;
    }
}

extern "C" void kernel_launch(void* const* d_in, const int* in_sizes, int n_in,
                              void* d_out, int out_size, void* d_ws, size_t ws_size,
                              hipStream_t stream) {
    const float* z = (const float*)d_in[0];           // [32,256,32,32]
    const float* E = (const float*)d_in[1];           // [1024,256]
    float* out = (float*)d_out;
    float* ws  = (float*)d_ws;

    half_t* zh  = (half_t*)out;                       // scratch in z_q region
    half_t* ehp = (half_t*)(out + EH_F);
    float* esqp = out + ESQ_F;
    float* zsqp = out + ZSQ_F;

    hipMemsetAsync(d_ws, 0, 64, stream);
    esq_kernel  <<<NUM_CODES / 4, 256, 0, stream>>>(E, esqp);
    ecvt_kernel <<<NUM_CODES * EMBED_DIM / 1024, 256, 0, stream>>>(E, ehp);
    zprep_kernel<<<NPIX / 64, 256, 0, stream>>>(z, zh, zsqp);
    vq_mfma     <<<NPIX / 64, 256, 0, stream>>>(z, E, zh, ehp, esqp, zsqp, out, ws);
    gather_kernel<<<NPIX / 64, 256, 0, stream>>>(E, out, ws);
}